// Round 2
// baseline (4001.159 us; speedup 1.0000x reference)
//
#include <hip/hip_runtime.h>

// ApsMultiheadAttention: E=1024 H=16 D=64 L=S=2048 N=2, fp32 throughout.
// Outputs: context (L,N,E) then att (N,L,S), concatenated in d_out.
//
// Pipeline:
//   gemm<1>: Q = query @ Wq^T + bq  -> q_s  (N,H,L,D)
//   gemm<2>: K = key   @ Wk^T + bk  -> kt_s (N,H,D,S)   (transposed for coalesced QK^T)
//   gemm<1>: V = value @ Wv^T + bv  -> v_s  (N,H,S,D)
//   attn   : per (n, 16-row l-block), loop 16 heads: logits->scratch, softmax,
//            att += p/H (exclusive RMW), ctx = P@V  -> ctx (L,N,E)
//   gemm<0>: out = ctx @ out_w^T + out_b -> d_out
//
// All fp32 (no fp32 MFMA on CDNA4; vector ALU). Still correctness-first: no
// bench has run yet. Changes vs round 0: attn 512 threads (2 waves/SIMD for
// latency hiding), GEMM LDS rows padded 128->132 (kills 4-way write conflict).

#define EDIM   1024
#define HNUM   16
#define DDIM   64
#define LQ     2048
#define SK     2048
#define NBATCH 2

#define NEG_BIG (-3.0e38f)

__device__ __forceinline__ float wave_max_f(float v) {
#pragma unroll
  for (int o = 32; o > 0; o >>= 1) v = fmaxf(v, __shfl_xor(v, o));
  return v;
}
__device__ __forceinline__ float wave_sum_f(float v) {
#pragma unroll
  for (int o = 32; o > 0; o >>= 1) v += __shfl_xor(v, o);
  return v;
}

// ---------------------------------------------------------------------------
// GEMM: C = A(MxK) @ W(NcxK)^T + bias.  Tile 128x128, BK=16, 256 threads,
// 8x8 micro-tile as 2x2 quadrants of 4x4 (conflict-free LDS frag reads,
// coalesced float-stores). EPI: 0 plain row-major; 1 scatter (N,H,R,D);
// 2 scatter (N,H,D,R).  GEMM rows are (row, n) with n fastest (m = row*N + n).
// LDS rows padded to 132 floats (528B, 16B-aligned): staging writes go from
// 4-way bank conflict to 2-way (free).
template <int EPI>
__global__ __launch_bounds__(256) void gemm_k(
    const float* __restrict__ A, const float* __restrict__ W,
    const float* __restrict__ bias, float* __restrict__ C,
    const int M, const int K, const int Nc, const int R)
{
  __shared__ float As[16][132];
  __shared__ float Bs[16][132];
  const int t  = threadIdx.x;
  const int m0 = blockIdx.y * 128;
  const int n0 = blockIdx.x * 128;
  const int lr = t >> 2;          // 0..63 staging row
  const int lk = (t & 3) << 2;    // k sub-offset 0,4,8,12
  const int tx = t & 15;
  const int ty = t >> 4;

  float acc[2][2][4][4];
#pragma unroll
  for (int a = 0; a < 2; ++a)
#pragma unroll
    for (int b = 0; b < 2; ++b)
#pragma unroll
      for (int i = 0; i < 4; ++i)
#pragma unroll
        for (int j = 0; j < 4; ++j) acc[a][b][i][j] = 0.f;

  float4 ra0, ra1, rb0, rb1;
  ra0 = *(const float4*)&A[(size_t)(m0 + lr) * K + lk];
  ra1 = *(const float4*)&A[(size_t)(m0 + lr + 64) * K + lk];
  rb0 = *(const float4*)&W[(size_t)(n0 + lr) * K + lk];
  rb1 = *(const float4*)&W[(size_t)(n0 + lr + 64) * K + lk];

  for (int k0 = 0; k0 < K; k0 += 16) {
    __syncthreads();
    As[lk+0][lr]    = ra0.x; As[lk+1][lr]    = ra0.y; As[lk+2][lr]    = ra0.z; As[lk+3][lr]    = ra0.w;
    As[lk+0][lr+64] = ra1.x; As[lk+1][lr+64] = ra1.y; As[lk+2][lr+64] = ra1.z; As[lk+3][lr+64] = ra1.w;
    Bs[lk+0][lr]    = rb0.x; Bs[lk+1][lr]    = rb0.y; Bs[lk+2][lr]    = rb0.z; Bs[lk+3][lr]    = rb0.w;
    Bs[lk+0][lr+64] = rb1.x; Bs[lk+1][lr+64] = rb1.y; Bs[lk+2][lr+64] = rb1.z; Bs[lk+3][lr+64] = rb1.w;
    __syncthreads();
    const int kn = k0 + 16;
    if (kn < K) {  // prefetch next tile while computing this one
      ra0 = *(const float4*)&A[(size_t)(m0 + lr) * K + kn + lk];
      ra1 = *(const float4*)&A[(size_t)(m0 + lr + 64) * K + kn + lk];
      rb0 = *(const float4*)&W[(size_t)(n0 + lr) * K + kn + lk];
      rb1 = *(const float4*)&W[(size_t)(n0 + lr + 64) * K + kn + lk];
    }
#pragma unroll
    for (int kk = 0; kk < 16; ++kk) {
      const float4 a0 = *(const float4*)&As[kk][ty * 4];
      const float4 a1 = *(const float4*)&As[kk][ty * 4 + 64];
      const float4 b0 = *(const float4*)&Bs[kk][tx * 4];
      const float4 b1 = *(const float4*)&Bs[kk][tx * 4 + 64];
      const float av[2][4] = {{a0.x,a0.y,a0.z,a0.w},{a1.x,a1.y,a1.z,a1.w}};
      const float bv[2][4] = {{b0.x,b0.y,b0.z,b0.w},{b1.x,b1.y,b1.z,b1.w}};
#pragma unroll
      for (int qi = 0; qi < 2; ++qi)
#pragma unroll
        for (int i = 0; i < 4; ++i)
#pragma unroll
          for (int qj = 0; qj < 2; ++qj)
#pragma unroll
            for (int j = 0; j < 4; ++j)
              acc[qi][qj][i][j] = fmaf(av[qi][i], bv[qj][j], acc[qi][qj][i][j]);
    }
  }

#pragma unroll
  for (int qi = 0; qi < 2; ++qi)
#pragma unroll
    for (int i = 0; i < 4; ++i) {
      const int gr = m0 + qi * 64 + ty * 4 + i;
      const int row = gr / NBATCH;   // l or s
      const int nb  = gr % NBATCH;
#pragma unroll
      for (int qj = 0; qj < 2; ++qj)
#pragma unroll
        for (int j = 0; j < 4; ++j) {
          const int gc = n0 + qj * 64 + tx * 4 + j;
          const float val = acc[qi][qj][i][j] + bias[gc];
          if constexpr (EPI == 0) {
            C[(size_t)gr * Nc + gc] = val;
          } else {
            const int h = gc >> 6, d = gc & 63;
            if constexpr (EPI == 1)
              C[(((size_t)nb * HNUM + h) * R + row) * DDIM + d] = val;       // (N,H,R,D)
            else
              C[(((size_t)nb * HNUM + h) * DDIM + d) * (size_t)R + row] = val; // (N,H,D,R)
          }
        }
    }
}

// ---------------------------------------------------------------------------
// Attention: grid = N * (L/16) = 256 blocks, 512 threads (8 waves: 2/SIMD).
// Block owns 16 q-rows of batch n, loops all 16 heads (att-mean is an
// exclusive global RMW: store on h==0, += after). Logits live in a per-block
// 16x2048 fp32 slab in d_ws (L2-resident).
//
// Phases per head:
//  A1: 4 groups x 128 thr, group g owns rows g*4..g*4+3, acc[4][4] over s.
//  A2: 8 waves x 2 rows: p=exp(lg-m) back to scr, row-sum -> rinv (regs+LDS).
//  B1: same waves write att (wave-local scr rows, own rinv in regs).
//  B2: 8 waves = 4 row-groups x 2 s-halves; partial PV -> LDS; combine.
__global__ __launch_bounds__(512) void attn_k(
    const float* __restrict__ qs, const float* __restrict__ kts,
    const float* __restrict__ vs, const float* __restrict__ amask,
    const unsigned char* __restrict__ kpm,
    float* __restrict__ ctx, float* __restrict__ att, float* __restrict__ sscr)
{
  const int t  = threadIdx.x;
  const int wg = blockIdx.x;
  const int n  = wg >> 7;
  const int l0 = (wg & 127) * 16;
  float* scr = sscr + (size_t)wg * 16 * SK;

  __shared__ float q_lds[16 * DDIM];   // 4 KB
  __shared__ float part[2][16][DDIM];  // 8 KB PV partials
  __shared__ float wred[8][4];
  __shared__ float m_lds[16];
  __shared__ float rinv_lds[16];

  const int wid  = t >> 6;
  const int lane = t & 63;
  const int grp  = t >> 7;      // A1: row group (4 rows)
  const int sidx = t & 127;     // A1: s lane within group

  for (int h = 0; h < HNUM; ++h) {
    const int nh = n * HNUM + h;
    __syncthreads();  // protect q_lds/scr/part from previous head
    ((float2*)q_lds)[t] = ((const float2*)(qs + ((size_t)nh * LQ + l0) * DDIM))[t];
    __syncthreads();

    // ---- A1: logits = (Q K^T)/8 + mask -> scr; track row max ----
    const float* ktb = kts + (size_t)nh * DDIM * SK;
    float rmax[4];
#pragma unroll
    for (int r = 0; r < 4; ++r) rmax[r] = NEG_BIG;

    for (int jj = 0; jj < 4; ++jj) {
      const int sb = jj * 512 + sidx;     // this thread's 4 s-columns: sb + c*128
      float acc[4][4];
#pragma unroll
      for (int r = 0; r < 4; ++r)
#pragma unroll
        for (int c = 0; c < 4; ++c) acc[r][c] = 0.f;

      for (int d4 = 0; d4 < DDIM; d4 += 4) {
        float4 qv[4];
#pragma unroll
        for (int r = 0; r < 4; ++r)
          qv[r] = *(const float4*)&q_lds[(grp * 4 + r) * DDIM + d4];   // LDS broadcast
#pragma unroll
        for (int d2 = 0; d2 < 4; ++d2) {
          float kc[4];
#pragma unroll
          for (int c = 0; c < 4; ++c)
            kc[c] = ktb[(size_t)(d4 + d2) * SK + sb + c * 128];        // coalesced (s fastest)
#pragma unroll
          for (int r = 0; r < 4; ++r) {
            const float qq = (d2 == 0) ? qv[r].x : (d2 == 1) ? qv[r].y
                           : (d2 == 2) ? qv[r].z : qv[r].w;
#pragma unroll
            for (int c = 0; c < 4; ++c) acc[r][c] = fmaf(qq, kc[c], acc[r][c]);
          }
        }
      }
#pragma unroll
      for (int c = 0; c < 4; ++c) {
        const int s = sb + c * 128;
        const bool kill = (kpm[n * SK + s] != 0);
#pragma unroll
        for (int r = 0; r < 4; ++r) {
          const int row = grp * 4 + r;
          float lg = acc[r][c] * 0.125f + amask[(size_t)(l0 + row) * SK + s];
          if (kill) lg = NEG_BIG;
          rmax[r] = fmaxf(rmax[r], lg);
          scr[(size_t)row * SK + s] = lg;
        }
      }
    }
    // cross-wave row-max: waves {2g, 2g+1} both cover rows g*4..g*4+3
#pragma unroll
    for (int r = 0; r < 4; ++r) rmax[r] = wave_max_f(rmax[r]);
    if (lane == 0) {
#pragma unroll
      for (int r = 0; r < 4; ++r) wred[wid][r] = rmax[r];
    }
    __syncthreads();
    if (t < 16) {   // row t = (t>>2)*4 + (t&3)
      const int g2 = (t >> 2) * 2;
      m_lds[t] = fmaxf(wred[g2][t & 3], wred[g2 + 1][t & 3]);
    }
    __syncthreads();

    // ---- A2: p' = exp(logit - m), write back, row-sum ----  (wave: 2 rows)
    const int r2 = wid * 2;
    float mrow[2] = { m_lds[r2], m_lds[r2 + 1] };
    float sums[2] = { 0.f, 0.f };
#pragma unroll 4
    for (int i = 0; i < 32; ++i) {
      const int s = lane + i * 64;
#pragma unroll
      for (int r = 0; r < 2; ++r) {
        const size_t idx = (size_t)(r2 + r) * SK + s;
        const float p = __expf(scr[idx] - mrow[r]);
        scr[idx] = p;
        sums[r] += p;
      }
    }
    float rinv[2];
#pragma unroll
    for (int r = 0; r < 2; ++r) rinv[r] = 1.0f / wave_sum_f(sums[r]);
    if (lane == 0) { rinv_lds[r2] = rinv[0]; rinv_lds[r2 + 1] = rinv[1]; }

    // ---- B1: att[n,l,s] (+)= p/(sum*H); wave-local rows, exclusive RMW ----
    {
      const float c16 = 1.0f / (float)HNUM;
#pragma unroll 4
      for (int i = 0; i < 32; ++i) {
        const int s = lane + i * 64;
#pragma unroll
        for (int r = 0; r < 2; ++r) {
          float* ap = att + ((size_t)n * LQ + l0 + r2 + r) * SK + s;
          const float v = scr[(size_t)(r2 + r) * SK + s] * (rinv[r] * c16);
          if (h == 0) *ap = v;
          else        *ap += v;
        }
      }
    }
    __syncthreads();  // scr p-values + rinv_lds visible to all waves

    // ---- B2: PV partials. wave = (row-group rgrp, s-half shalf) ----
    {
      const int rgrp  = wid & 3;
      const int shalf = wid >> 2;
      const float* vb = vs + (size_t)nh * SK * DDIM + lane;
      const float* s0 = scr + (size_t)(rgrp * 4) * SK;
      float a4[4] = {0.f, 0.f, 0.f, 0.f};
      const int sbeg = shalf * (SK / 2);
      for (int s = sbeg; s < sbeg + SK / 2; s += 4) {
        float4 p[4];
#pragma unroll
        for (int r = 0; r < 4; ++r)
          p[r] = *(const float4*)&s0[(size_t)r * SK + s];   // wave-uniform broadcast
        const float v0 = vb[(size_t)(s + 0) * DDIM];
        const float v1 = vb[(size_t)(s + 1) * DDIM];
        const float v2 = vb[(size_t)(s + 2) * DDIM];
        const float v3 = vb[(size_t)(s + 3) * DDIM];
#pragma unroll
        for (int r = 0; r < 4; ++r)
          a4[r] = fmaf(p[r].x, v0, fmaf(p[r].y, v1, fmaf(p[r].z, v2, fmaf(p[r].w, v3, a4[r]))));
      }
#pragma unroll
      for (int r = 0; r < 4; ++r) part[shalf][rgrp * 4 + r][lane] = a4[r];
    }
    __syncthreads();

    // ---- combine: ctx[l, n, h*64+d] = (part0+part1) * rinv ----
    {
      const int row = t >> 6;        // 0..7, also handle row+8
      const int dd  = t & 63;
#pragma unroll
      for (int rr = 0; rr < 2; ++rr) {
        const int r = row + rr * 8;
        const float val = (part[0][r][dd] + part[1][r][dd]) * rinv_lds[r];
        ctx[((size_t)(l0 + r) * NBATCH + n) * EDIM + h * DDIM + dd] = val;
      }
    }
  }
}

// ---------------------------------------------------------------------------
extern "C" void kernel_launch(void* const* d_in, const int* in_sizes, int n_in,
                              void* d_out, int out_size, void* d_ws, size_t ws_size,
                              hipStream_t stream)
{
  const float*         query = (const float*)d_in[0];
  const float*         key   = (const float*)d_in[1];
  const float*         value = (const float*)d_in[2];
  const unsigned char* kpm   = (const unsigned char*)d_in[3];  // all-false bools
  const float*         amask = (const float*)d_in[4];
  const float*         ipw   = (const float*)d_in[5];
  const float*         ipb   = (const float*)d_in[6];
  const float*         outw  = (const float*)d_in[7];
  const float*         outb  = (const float*)d_in[8];

  float* outp = (float*)d_out;                          // context (L,N,E)
  float* att  = outp + (size_t)LQ * NBATCH * EDIM;      // att (N,L,S)

  // workspace layout (fp32): q_s 16MB | kt_s 16MB | v_s 16MB | ctx 16MB | logit scratch 32MB
  const size_t nQ = (size_t)NBATCH * HNUM * LQ * DDIM;  // 4,194,304
  const size_t needed = (3 * nQ + (size_t)LQ * NBATCH * EDIM + (size_t)256 * 16 * SK) * 4;
  if (ws_size < needed) return;  // fail loudly via poisoned output rather than corrupt memory

  float* ws   = (float*)d_ws;
  float* q_s  = ws;
  float* kt_s = q_s  + nQ;
  float* v_s  = kt_s + nQ;
  float* ctx  = v_s  + nQ;
  float* sscr = ctx  + (size_t)LQ * NBATCH * EDIM;

  const int M = LQ * NBATCH;                 // 4096 rows for every GEMM
  dim3 gg(EDIM / 128, M / 128);              // (8, 32) = 256 blocks

  gemm_k<1><<<gg, 256, 0, stream>>>(query, ipw,                   ipb,            q_s,  M, EDIM, EDIM, LQ);
  gemm_k<2><<<gg, 256, 0, stream>>>(key,   ipw + EDIM * EDIM,     ipb + EDIM,     kt_s, M, EDIM, EDIM, SK);
  gemm_k<1><<<gg, 256, 0, stream>>>(value, ipw + 2 * EDIM * EDIM, ipb + 2 * EDIM, v_s,  M, EDIM, EDIM, SK);
  attn_k<<<NBATCH * (LQ / 16), 512, 0, stream>>>(q_s, kt_s, v_s, amask, kpm, ctx, att, sscr);
  gemm_k<0><<<gg, 256, 0, stream>>>(ctx, outw, outb, outp, M, EDIM, EDIM, LQ);
}